// Round 1
// baseline (435.459 us; speedup 1.0000x reference)
//
#include <hip/hip_runtime.h>
#include <stdint.h>

#define B_ 8
#define C_ 256
#define O_ 256
#define H_ 64
#define W_ 64
#define HW_ 4096
#define K2_ 9

typedef __attribute__((ext_vector_type(8))) short bf16x8;
typedef __attribute__((ext_vector_type(4))) float f32x4;

__device__ __forceinline__ unsigned short f2bf(float f) {
    union { float f; unsigned u; } v; v.f = f;
    unsigned r = v.u + 0x7FFFu + ((v.u >> 16) & 1u);
    return (unsigned short)(r >> 16);
}

// ---------- prep: offset-conv weights -> [c*9+tap][20] (pad 18->20) ----------
__global__ void k_prep_woff(const float* __restrict__ w_off, float* __restrict__ wofT) {
    int idx = blockIdx.x * 256 + threadIdx.x;
    if (idx >= 2304 * 20) return;
    int ct = idx / 20, oc = idx - ct * 20;
    float v = 0.f;
    if (oc < 18) {
        int c = ct / 9, tap = ct - c * 9;
        v = w_off[(oc * C_ + c) * 9 + tap];
    }
    wofT[idx] = v;
}

// ---------- prep: w_def -> bf16 MFMA A-fragment lane order ----------
// wfrag[(((k2*8+cc)*16+mfg)*64+lane)*8 + j] = bf16( w_def[o=mfg*16+(lane&15)][c=cc*32+(lane>>4)*8+j][k2] )
__global__ void k_prep_wdef(const float* __restrict__ w_def, unsigned short* __restrict__ wfrag) {
    int idx = blockIdx.x * 256 + threadIdx.x;
    if (idx >= 9 * 8 * 16 * 64) return;
    int lane = idx & 63;
    int mfg = (idx >> 6) & 15;
    int cc = (idx >> 10) & 7;
    int k2 = idx >> 13;
    int o = mfg * 16 + (lane & 15);
    int cb = cc * 32 + (lane >> 4) * 8;
    bf16x8 pk;
#pragma unroll
    for (int j = 0; j < 8; ++j)
        pk[j] = (short)f2bf(w_def[(size_t)(o * C_ + cb + j) * K2_ + k2]);
    *reinterpret_cast<bf16x8*>(wfrag + (size_t)idx * 8) = pk;
}

// ---------- offset conv: relu(x) * w_off + b_off -> offs[b][18][h][w] ----------
__global__ __launch_bounds__(256) void k_offconv(const float* __restrict__ x,
                                                 const float* __restrict__ wofT,
                                                 const float* __restrict__ b_off,
                                                 float* __restrict__ offs) {
    int bh = blockIdx.x;
    int b = bh >> 6, h = bh & 63;
    int tid = threadIdx.x;
    int lane = tid & 63;   // pixel w
    int g = tid >> 6;      // channel group (wave)
    float acc[18];
#pragma unroll
    for (int i = 0; i < 18; ++i) acc[i] = 0.f;
    const float* xb = x + ((size_t)b * C_ + g * 64) * HW_;
    for (int cl = 0; cl < 64; ++cl) {
        const float* xp = xb + (size_t)cl * HW_;
        float xv[9];
#pragma unroll
        for (int ky = 0; ky < 3; ++ky) {
            int y = h + ky - 1;
            bool yv = (unsigned)y < 64u;
#pragma unroll
            for (int kx = 0; kx < 3; ++kx) {
                int xx = lane + kx - 1;
                bool v = yv && ((unsigned)xx < 64u);
                float t = v ? xp[y * 64 + xx] : 0.f;
                xv[ky * 3 + kx] = t > 0.f ? t : 0.f;
            }
        }
        const float* wp = wofT + (size_t)((g * 64 + cl) * 9) * 20;
#pragma unroll
        for (int tap = 0; tap < 9; ++tap) {
            float xvt = xv[tap];
#pragma unroll
            for (int q = 0; q < 18; ++q)
                acc[q] = fmaf(xvt, wp[tap * 20 + q], acc[q]);
        }
    }
    __shared__ float red[4][18][64];
#pragma unroll
    for (int q = 0; q < 18; ++q) red[g][q][lane] = acc[q];
    __syncthreads();
    for (int idx = tid; idx < 18 * 64; idx += 256) {
        int oc = idx >> 6, w = idx & 63;
        float s = red[0][oc][w] + red[1][oc][w] + red[2][oc][w] + red[3][oc][w] + b_off[oc];
        offs[(((size_t)b * 18 + oc) * 64 + h) * 64 + w] = s;
    }
}

// ---------- fused bilinear gather + MFMA GEMM ----------
// Block = (b,h): out tile M=256 (all O), N=64 (pixels of the row), K = 9 taps * 256 c.
__global__ __launch_bounds__(256) void k_deform(const float* __restrict__ x,
                                                const unsigned short* __restrict__ wfrag,
                                                const float* __restrict__ offs,
                                                float* __restrict__ out) {
    int bh = blockIdx.x;
    int b = bh >> 6, h = bh & 63;
    int tid = threadIdx.x;
    int lane = tid & 63;
    int wm = tid >> 6;   // wave: owns o-range [wm*64, wm*64+64)

    __shared__ float s_wy[9][64], s_wx[9][64];
    __shared__ int s_y0[9][64], s_x0[9][64];
    __shared__ __align__(16) unsigned short s_samp[64][48];  // [pixel][c_local], pad 32->48

    // Phase A: per-(tap,pixel) sample geometry
    for (int idx = tid; idx < 9 * 64; idx += 256) {
        int k2 = idx >> 6;
        int p = idx & 63;
        float dy = offs[(((size_t)b * 18 + k2 * 2 + 0) * 64 + h) * 64 + p];
        float dx = offs[(((size_t)b * 18 + k2 * 2 + 1) * 64 + h) * 64 + p];
        float py = (float)(h - 1 + k2 / 3) + dy;
        float px = (float)(p - 1 + k2 % 3) + dx;
        float y0f = floorf(py), x0f = floorf(px);
        s_wy[k2][p] = py - y0f;
        s_wx[k2][p] = px - x0f;
        s_y0[k2][p] = (int)y0f;
        s_x0[k2][p] = (int)x0f;
    }
    __syncthreads();

    f32x4 acc[4][4];
#pragma unroll
    for (int i = 0; i < 4; ++i)
#pragma unroll
        for (int j = 0; j < 4; ++j) acc[i][j] = (f32x4){0.f, 0.f, 0.f, 0.f};

    const float* xb = x + (size_t)b * C_ * HW_;

    for (int k2 = 0; k2 < 9; ++k2) {
        int y0 = s_y0[k2][lane], x0 = s_x0[k2][lane];
        float wy = s_wy[k2][lane], wx = s_wx[k2][lane];
        float w00 = (1.f - wy) * (1.f - wx), w01 = (1.f - wy) * wx;
        float w10 = wy * (1.f - wx), w11 = wy * wx;
        bool vy0 = (unsigned)y0 < 64u, vy1 = (unsigned)(y0 + 1) < 64u;
        bool vx0 = (unsigned)x0 < 64u, vx1 = (unsigned)(x0 + 1) < 64u;
        if (!(vy0 && vx0)) w00 = 0.f;
        if (!(vy0 && vx1)) w01 = 0.f;
        if (!(vy1 && vx0)) w10 = 0.f;
        if (!(vy1 && vx1)) w11 = 0.f;
        int y0c = y0 < 0 ? 0 : (y0 > 63 ? 63 : y0);
        int y1t = y0 + 1;
        int y1c = y1t < 0 ? 0 : (y1t > 63 ? 63 : y1t);
        int x0c = x0 < 0 ? 0 : (x0 > 63 ? 63 : x0);
        int x1t = x0 + 1;
        int x1c = x1t < 0 ? 0 : (x1t > 63 ? 63 : x1t);
        int i00 = y0c * 64 + x0c, i01 = y0c * 64 + x1c;
        int i10 = y1c * 64 + x0c, i11 = y1c * 64 + x1c;

        for (int cc = 0; cc < 8; ++cc) {
            // gather 8 channels for my pixel (lane) into bf16
            const float* xc = xb + (size_t)(cc * 32 + wm * 8) * HW_;
            bf16x8 pk;
#pragma unroll
            for (int j = 0; j < 8; ++j) {
                const float* xp = xc + (size_t)j * HW_;
                float v00 = fmaxf(xp[i00], 0.f);
                float v01 = fmaxf(xp[i01], 0.f);
                float v10 = fmaxf(xp[i10], 0.f);
                float v11 = fmaxf(xp[i11], 0.f);
                float s = w00 * v00 + w01 * v01 + w10 * v10 + w11 * v11;
                pk[j] = (short)f2bf(s);
            }
            *reinterpret_cast<bf16x8*>(&s_samp[lane][wm * 8]) = pk;
            __syncthreads();

            // B fragments (samp) from LDS
            bf16x8 bfr[4];
#pragma unroll
            for (int nf = 0; nf < 4; ++nf) {
                int n = nf * 16 + (lane & 15);
                bfr[nf] = *reinterpret_cast<const bf16x8*>(&s_samp[n][(lane >> 4) * 8]);
            }
            // A fragments (weights) pre-swizzled in global, fully coalesced
            const bf16x8* wf = reinterpret_cast<const bf16x8*>(wfrag) +
                               (size_t)(((k2 * 8 + cc) * 16 + wm * 4) * 64 + lane);
#pragma unroll
            for (int mf = 0; mf < 4; ++mf) {
                bf16x8 af = wf[(size_t)mf * 64];
#pragma unroll
                for (int nf = 0; nf < 4; ++nf)
                    acc[mf][nf] = __builtin_amdgcn_mfma_f32_16x16x32_bf16(af, bfr[nf], acc[mf][nf], 0, 0, 0);
            }
            __syncthreads();
        }
    }

    // epilogue: C/D layout col=lane&15 (pixel), row=(lane>>4)*4+reg (o)
    float* op = out + (size_t)b * O_ * HW_ + h * 64;
#pragma unroll
    for (int mf = 0; mf < 4; ++mf)
#pragma unroll
        for (int nf = 0; nf < 4; ++nf)
#pragma unroll
            for (int r = 0; r < 4; ++r) {
                int o = wm * 64 + mf * 16 + (lane >> 4) * 4 + r;
                int w = nf * 16 + (lane & 15);
                op[(size_t)o * HW_ + w] = acc[mf][nf][r];
            }
}

extern "C" void kernel_launch(void* const* d_in, const int* in_sizes, int n_in,
                              void* d_out, int out_size, void* d_ws, size_t ws_size,
                              hipStream_t stream) {
    const float* x = (const float*)d_in[0];
    const float* w_off = (const float*)d_in[1];
    const float* b_off = (const float*)d_in[2];
    const float* w_def = (const float*)d_in[3];
    float* out = (float*)d_out;
    char* ws = (char*)d_ws;

    float* offs = (float*)ws;                                    // 8*18*64*64*4   = 2359296 B
    float* wofT = (float*)(ws + 2359296);                        // 2304*20*4      = 184320 B
    unsigned short* wfrag = (unsigned short*)(ws + 2359296 + 184320); // 73728*8*2 = 1179648 B

    k_prep_woff<<<(2304 * 20 + 255) / 256, 256, 0, stream>>>(w_off, wofT);
    k_prep_wdef<<<(9 * 8 * 16 * 64 + 255) / 256, 256, 0, stream>>>(w_def, wfrag);
    k_offconv<<<512, 256, 0, stream>>>(x, wofT, b_off, offs);
    k_deform<<<512, 256, 0, stream>>>(x, wfrag, offs, out);
}

// Round 2
// 153.718 us; speedup vs baseline: 2.8328x; 2.8328x over previous
//
#include <hip/hip_runtime.h>
#include <stdint.h>

#define B_ 8
#define C_ 256
#define O_ 256
#define HW_ 4096

typedef __attribute__((ext_vector_type(8))) short bf16x8;
typedef __attribute__((ext_vector_type(4))) float f32x4;

__device__ __forceinline__ unsigned short f2bf(float f) {
    union { float f; unsigned u; } v; v.f = f;
    unsigned r = v.u + 0x7FFFu + ((v.u >> 16) & 1u);
    return (unsigned short)(r >> 16);
}
__device__ __forceinline__ float bf2f(short s) {
    union { unsigned u; float f; } v; v.u = ((unsigned)(unsigned short)s) << 16;
    return v.f;
}

// ---------- prep: x (NCHW f32) -> xT (NHWC bf16, relu applied) ----------
__global__ __launch_bounds__(256) void k_nhwc(const float* __restrict__ x,
                                              unsigned short* __restrict__ xT) {
    int bh = blockIdx.x;
    int b = bh & 7, h = bh >> 3;
    int t = threadIdx.x, px = t & 63, wg = t >> 6;
#pragma unroll
    for (int i = 0; i < 4; ++i) {
        int c0 = i * 64 + wg * 16;
        unsigned short v[16];
#pragma unroll
        for (int j = 0; j < 16; ++j) {
            float f = x[((size_t)(b * C_ + c0 + j)) * HW_ + h * 64 + px];
            v[j] = f2bf(fmaxf(f, 0.f));
        }
        unsigned short* dst = xT + ((size_t)((b * 64 + h) * 64 + px)) * C_ + c0;
        *reinterpret_cast<bf16x8*>(dst) = *reinterpret_cast<const bf16x8*>(v);
        *reinterpret_cast<bf16x8*>(dst + 8) = *reinterpret_cast<const bf16x8*>(v + 8);
    }
}

// ---------- prep: w_def -> bf16 MFMA A-frags [k2][ccc8][mfg16][lane64][8] ----------
__global__ void k_prep_wdef(const float* __restrict__ w_def, unsigned short* __restrict__ wfrag) {
    int idx = blockIdx.x * 256 + threadIdx.x;
    if (idx >= 9 * 8 * 16 * 64) return;
    int lane = idx & 63;
    int mfg = (idx >> 6) & 15;
    int ccc = (idx >> 10) & 7;
    int k2 = idx >> 13;
    int o = mfg * 16 + (lane & 15);
    int cb = ccc * 32 + (lane >> 4) * 8;
    bf16x8 pk;
#pragma unroll
    for (int j = 0; j < 8; ++j)
        pk[j] = (short)f2bf(w_def[(size_t)(o * C_ + cb + j) * 9 + k2]);
    *reinterpret_cast<bf16x8*>(wfrag + (size_t)idx * 8) = pk;
}

// ---------- prep: w_off -> bf16 MFMA A-frags [k2][ccc8][mfg2][lane64][8] (M pad 18->32) ----------
__global__ void k_prep_woffrag(const float* __restrict__ w_off, unsigned short* __restrict__ wfr) {
    int idx = blockIdx.x * 256 + threadIdx.x;
    if (idx >= 9 * 8 * 2 * 64) return;
    int lane = idx & 63;
    int mfg = (idx >> 6) & 1;
    int ccc = (idx >> 7) & 7;
    int k2 = idx >> 10;
    int o = mfg * 16 + (lane & 15);
    int cb = ccc * 32 + (lane >> 4) * 8;
    bf16x8 pk;
#pragma unroll
    for (int j = 0; j < 8; ++j)
        pk[j] = (o < 18) ? (short)f2bf(w_off[(size_t)(o * C_ + cb + j) * 9 + k2]) : (short)0;
    *reinterpret_cast<bf16x8*>(wfr + (size_t)idx * 8) = pk;
}

// ---------- offset conv via MFMA: offs[b][18][h][w] ----------
// Block (b,h): M=32(18 used), N=64 px, K=2304. Wave wm owns pixels [wm*16, wm*16+16).
__global__ __launch_bounds__(256) void k_offconv2(const unsigned short* __restrict__ xT,
                                                  const unsigned short* __restrict__ wfr,
                                                  const float* __restrict__ b_off,
                                                  float* __restrict__ offs) {
    int bh = blockIdx.x;
    int b = bh & 7, h = bh >> 3;
    int tid = threadIdx.x, lane = tid & 63, wm = tid >> 6;
    __shared__ __align__(16) unsigned short s_b[64 * 64];  // [px][64ch], 128B rows, XOR-swizzled
    f32x4 acc[2];
    acc[0] = (f32x4){0.f, 0.f, 0.f, 0.f};
    acc[1] = (f32x4){0.f, 0.f, 0.f, 0.f};
    const unsigned short* xb = xT + (size_t)b * HW_ * C_;

    for (int k2 = 0; k2 < 9; ++k2) {
        int y = h + k2 / 3 - 1;
        int xp = lane + k2 % 3 - 1;
        bool v = ((unsigned)y < 64u) && ((unsigned)xp < 64u);
        int yc = y < 0 ? 0 : (y > 63 ? 63 : y);
        int xc = xp < 0 ? 0 : (xp > 63 ? 63 : xp);
        int pidx = (yc * 64 + xc) * C_;
        for (int cc = 0; cc < 4; ++cc) {
#pragma unroll
            for (int hh = 0; hh < 2; ++hh) {
                int ch = cc * 64 + hh * 32 + wm * 8;
                bf16x8 raw = *reinterpret_cast<const bf16x8*>(xb + pidx + ch);
                if (!v) raw = (bf16x8){0, 0, 0, 0, 0, 0, 0, 0};
                int oct = wm + 4 * hh;
                int slot = (oct ^ (lane & 7)) & 7;
                *reinterpret_cast<bf16x8*>(&s_b[lane * 64 + slot * 8]) = raw;
            }
            __syncthreads();
#pragma unroll
            for (int kk = 0; kk < 2; ++kk) {
                int n = wm * 16 + (lane & 15);
                int oct = kk * 4 + (lane >> 4);
                int slot = (oct ^ (n & 7)) & 7;
                bf16x8 bf = *reinterpret_cast<const bf16x8*>(&s_b[n * 64 + slot * 8]);
                const bf16x8* wp = reinterpret_cast<const bf16x8*>(wfr) +
                                   (size_t)((k2 * 8 + cc * 2 + kk) * 2) * 64 + lane;
                acc[0] = __builtin_amdgcn_mfma_f32_16x16x32_bf16(wp[0], bf, acc[0], 0, 0, 0);
                acc[1] = __builtin_amdgcn_mfma_f32_16x16x32_bf16(wp[64], bf, acc[1], 0, 0, 0);
            }
            __syncthreads();
        }
    }
    int px = wm * 16 + (lane & 15);
#pragma unroll
    for (int mf = 0; mf < 2; ++mf)
#pragma unroll
        for (int r = 0; r < 4; ++r) {
            int oc = mf * 16 + (lane >> 4) * 4 + r;
            if (oc < 18)
                offs[(((size_t)b * 18 + oc) * 64 + h) * 64 + px] = acc[mf][r] + b_off[oc];
        }
}

// ---------- fused bilinear gather (NHWC bf16) + MFMA GEMM ----------
// Block (b,h): M=256, N=64, K=2304 = 9 taps x 4 cc-chunks of 64ch (2 MFMA-K sub-steps each).
__global__ __launch_bounds__(256) void k_deform2(const unsigned short* __restrict__ xT,
                                                 const unsigned short* __restrict__ wfrag,
                                                 const float* __restrict__ offs,
                                                 float* __restrict__ out) {
    int bh = blockIdx.x;
    int b = bh & 7, h = bh >> 3;
    int tid = threadIdx.x, lane = tid & 63, wm = tid >> 6;

    __shared__ float s_py[9][64], s_px[9][64];
    __shared__ __align__(16) unsigned short s_samp[64 * 64];  // [px][64ch], swizzled

    for (int idx = tid; idx < 576; idx += 256) {
        int k2 = idx >> 6, p = idx & 63;
        float dy = offs[(((size_t)b * 18 + k2 * 2 + 0) * 64 + h) * 64 + p];
        float dx = offs[(((size_t)b * 18 + k2 * 2 + 1) * 64 + h) * 64 + p];
        s_py[k2][p] = (float)(h - 1 + k2 / 3) + dy;
        s_px[k2][p] = (float)(p - 1 + k2 % 3) + dx;
    }
    __syncthreads();

    f32x4 acc[4][4];
#pragma unroll
    for (int i = 0; i < 4; ++i)
#pragma unroll
        for (int j = 0; j < 4; ++j) acc[i][j] = (f32x4){0.f, 0.f, 0.f, 0.f};

    const unsigned short* xb = xT + (size_t)b * HW_ * C_;

    for (int k2 = 0; k2 < 9; ++k2) {
        float py = s_py[k2][lane], px = s_px[k2][lane];
        float y0f = floorf(py), x0f = floorf(px);
        float wy = py - y0f, wx = px - x0f;
        int y0 = (int)y0f, x0 = (int)x0f;
        float w00 = (1.f - wy) * (1.f - wx), w01 = (1.f - wy) * wx;
        float w10 = wy * (1.f - wx), w11 = wy * wx;
        bool vy0 = (unsigned)y0 < 64u, vy1 = (unsigned)(y0 + 1) < 64u;
        bool vx0 = (unsigned)x0 < 64u, vx1 = (unsigned)(x0 + 1) < 64u;
        if (!(vy0 && vx0)) w00 = 0.f;
        if (!(vy0 && vx1)) w01 = 0.f;
        if (!(vy1 && vx0)) w10 = 0.f;
        if (!(vy1 && vx1)) w11 = 0.f;
        int y0c = y0 < 0 ? 0 : (y0 > 63 ? 63 : y0);
        int y1 = y0 + 1, x1 = x0 + 1;
        int y1c = y1 < 0 ? 0 : (y1 > 63 ? 63 : y1);
        int x0c = x0 < 0 ? 0 : (x0 > 63 ? 63 : x0);
        int x1c = x1 < 0 ? 0 : (x1 > 63 ? 63 : x1);
        int i00 = (y0c * 64 + x0c) * C_, i01 = (y0c * 64 + x1c) * C_;
        int i10 = (y1c * 64 + x0c) * C_, i11 = (y1c * 64 + x1c) * C_;

        for (int cc = 0; cc < 4; ++cc) {
#pragma unroll
            for (int hh = 0; hh < 2; ++hh) {
                int ch = cc * 64 + hh * 32 + wm * 8;
                bf16x8 a0 = *reinterpret_cast<const bf16x8*>(xb + i00 + ch);
                bf16x8 a1 = *reinterpret_cast<const bf16x8*>(xb + i01 + ch);
                bf16x8 a2 = *reinterpret_cast<const bf16x8*>(xb + i10 + ch);
                bf16x8 a3 = *reinterpret_cast<const bf16x8*>(xb + i11 + ch);
                unsigned short pk[8];
#pragma unroll
                for (int j = 0; j < 8; ++j) {
                    float s = w00 * bf2f(a0[j]) + w01 * bf2f(a1[j]) +
                              w10 * bf2f(a2[j]) + w11 * bf2f(a3[j]);
                    pk[j] = f2bf(s);
                }
                int oct = wm + 4 * hh;
                int slot = (oct ^ (lane & 7)) & 7;
                *reinterpret_cast<bf16x8*>(&s_samp[lane * 64 + slot * 8]) =
                    *reinterpret_cast<const bf16x8*>(pk);
            }
            __syncthreads();
#pragma unroll
            for (int kk = 0; kk < 2; ++kk) {
                bf16x8 bfr[4];
#pragma unroll
                for (int nf = 0; nf < 4; ++nf) {
                    int n = nf * 16 + (lane & 15);
                    int oct = kk * 4 + (lane >> 4);
                    int slot = (oct ^ (n & 7)) & 7;
                    bfr[nf] = *reinterpret_cast<const bf16x8*>(&s_samp[n * 64 + slot * 8]);
                }
                const bf16x8* wf = reinterpret_cast<const bf16x8*>(wfrag) +
                                   (size_t)(((k2 * 8 + cc * 2 + kk) * 16 + wm * 4) * 64 + lane);
#pragma unroll
                for (int mf = 0; mf < 4; ++mf) {
                    bf16x8 af = wf[(size_t)mf * 64];
#pragma unroll
                    for (int nf = 0; nf < 4; ++nf)
                        acc[mf][nf] = __builtin_amdgcn_mfma_f32_16x16x32_bf16(af, bfr[nf], acc[mf][nf], 0, 0, 0);
                }
            }
            __syncthreads();
        }
    }

    float* op = out + (size_t)b * O_ * HW_ + h * 64;
#pragma unroll
    for (int mf = 0; mf < 4; ++mf)
#pragma unroll
        for (int nf = 0; nf < 4; ++nf)
#pragma unroll
            for (int r = 0; r < 4; ++r) {
                int o = wm * 64 + mf * 16 + (lane >> 4) * 4 + r;
                int w = nf * 16 + (lane & 15);
                op[(size_t)o * HW_ + w] = acc[mf][nf][r];
            }
}

extern "C" void kernel_launch(void* const* d_in, const int* in_sizes, int n_in,
                              void* d_out, int out_size, void* d_ws, size_t ws_size,
                              hipStream_t stream) {
    const float* x = (const float*)d_in[0];
    const float* w_off = (const float*)d_in[1];
    const float* b_off = (const float*)d_in[2];
    const float* w_def = (const float*)d_in[3];
    float* out = (float*)d_out;
    char* ws = (char*)d_ws;

    float* offs = (float*)ws;                                       // 2,359,296 B
    unsigned short* xT = (unsigned short*)(ws + 2359296);           // 16,777,216 B
    unsigned short* wfrag = (unsigned short*)(ws + 2359296 + 16777216);   // 1,179,648 B
    unsigned short* wofr = (unsigned short*)(ws + 2359296 + 16777216 + 1179648); // 147,456 B

    k_nhwc<<<512, 256, 0, stream>>>(x, xT);
    k_prep_wdef<<<288, 256, 0, stream>>>(w_def, wfrag);
    k_prep_woffrag<<<36, 256, 0, stream>>>(w_off, wofr);
    k_offconv2<<<512, 256, 0, stream>>>(xT, wofr, b_off, offs);
    k_deform2<<<512, 256, 0, stream>>>(xT, wfrag, offs, out);
}

// Round 3
// 130.639 us; speedup vs baseline: 3.3333x; 1.1767x over previous
//
#include <hip/hip_runtime.h>
#include <stdint.h>

#define B_ 8
#define C_ 256
#define O_ 256
#define HW_ 4096

typedef __attribute__((ext_vector_type(8))) short bf16x8;
typedef __attribute__((ext_vector_type(4))) float f32x4;

__device__ __forceinline__ unsigned short f2bf(float f) {
    union { float f; unsigned u; } v; v.f = f;
    unsigned r = v.u + 0x7FFFu + ((v.u >> 16) & 1u);
    return (unsigned short)(r >> 16);
}
__device__ __forceinline__ float bf2f(short s) {
    union { unsigned u; float f; } v; v.u = ((unsigned)(unsigned short)s) << 16;
    return v.f;
}

// ---------- prep: x (NCHW f32) -> xT (NHWC bf16, relu applied) ----------
__global__ __launch_bounds__(256) void k_nhwc(const float* __restrict__ x,
                                              unsigned short* __restrict__ xT) {
    int bh = blockIdx.x;
    int b = bh & 7, h = bh >> 3;
    int t = threadIdx.x, px = t & 63, wg = t >> 6;
#pragma unroll
    for (int i = 0; i < 4; ++i) {
        int c0 = i * 64 + wg * 16;
        unsigned short v[16];
#pragma unroll
        for (int j = 0; j < 16; ++j) {
            float f = x[((size_t)(b * C_ + c0 + j)) * HW_ + h * 64 + px];
            v[j] = f2bf(fmaxf(f, 0.f));
        }
        unsigned short* dst = xT + ((size_t)((b * 64 + h) * 64 + px)) * C_ + c0;
        *reinterpret_cast<bf16x8*>(dst) = *reinterpret_cast<const bf16x8*>(v);
        *reinterpret_cast<bf16x8*>(dst + 8) = *reinterpret_cast<const bf16x8*>(v + 8);
    }
}

// ---------- prep: w_def -> bf16 MFMA A-frags [k2][q8][mfg16][lane64][8] ----------
__global__ void k_prep_wdef(const float* __restrict__ w_def, unsigned short* __restrict__ wfrag) {
    int idx = blockIdx.x * 256 + threadIdx.x;
    if (idx >= 9 * 8 * 16 * 64) return;
    int lane = idx & 63;
    int mfg = (idx >> 6) & 15;
    int ccc = (idx >> 10) & 7;
    int k2 = idx >> 13;
    int o = mfg * 16 + (lane & 15);
    int cb = ccc * 32 + (lane >> 4) * 8;
    bf16x8 pk;
#pragma unroll
    for (int j = 0; j < 8; ++j)
        pk[j] = (short)f2bf(w_def[(size_t)(o * C_ + cb + j) * 9 + k2]);
    *reinterpret_cast<bf16x8*>(wfrag + (size_t)idx * 8) = pk;
}

// ---------- prep: w_off -> bf16 MFMA A-frags [k2][q8][mfg2][lane64][8] (M pad 18->32) ----------
__global__ void k_prep_woffrag(const float* __restrict__ w_off, unsigned short* __restrict__ wfr) {
    int idx = blockIdx.x * 256 + threadIdx.x;
    if (idx >= 9 * 8 * 2 * 64) return;
    int lane = idx & 63;
    int mfg = (idx >> 6) & 1;
    int ccc = (idx >> 7) & 7;
    int k2 = idx >> 10;
    int o = mfg * 16 + (lane & 15);
    int cb = ccc * 32 + (lane >> 4) * 8;
    bf16x8 pk;
#pragma unroll
    for (int j = 0; j < 8; ++j)
        pk[j] = (o < 18) ? (short)f2bf(w_off[(size_t)(o * C_ + cb + j) * 9 + k2]) : (short)0;
    *reinterpret_cast<bf16x8*>(wfr + (size_t)idx * 8) = pk;
}

// ---------- offset conv via MFMA, no LDS: B-frags loaded directly from NHWC ----------
__global__ __launch_bounds__(256) void k_offconv3(const unsigned short* __restrict__ xT,
                                                  const unsigned short* __restrict__ wofr,
                                                  const float* __restrict__ b_off,
                                                  float* __restrict__ offs) {
    int bh = blockIdx.x;
    int b = bh & 7, h = bh >> 3;
    int tid = threadIdx.x, lane = tid & 63, wm = tid >> 6;
    int px = wm * 16 + (lane & 15);
    int chl = (lane >> 4) * 8;
    f32x4 acc0 = (f32x4){0.f, 0.f, 0.f, 0.f};
    f32x4 acc1 = (f32x4){0.f, 0.f, 0.f, 0.f};
    const unsigned short* xb = xT + (size_t)b * HW_ * C_;
    const bf16x8 bz = (bf16x8){0, 0, 0, 0, 0, 0, 0, 0};
    for (int k2 = 0; k2 < 9; ++k2) {
        int y = h + k2 / 3 - 1;
        int xs = px + k2 % 3 - 1;
        bool v = ((unsigned)y < 64u) && ((unsigned)xs < 64u);
        int yc = y < 0 ? 0 : (y > 63 ? 63 : y);
        int xc = xs < 0 ? 0 : (xs > 63 ? 63 : xs);
        const unsigned short* xp = xb + (size_t)(yc * 64 + xc) * C_ + chl;
#pragma unroll
        for (int q = 0; q < 8; ++q) {  // q = cc*2+kk: 32-channel chunk
            bf16x8 bf = *reinterpret_cast<const bf16x8*>(xp + q * 32);
            if (!v) bf = bz;
            const bf16x8* wp = reinterpret_cast<const bf16x8*>(wofr) +
                               (size_t)((k2 * 8 + q) * 2) * 64 + lane;
            acc0 = __builtin_amdgcn_mfma_f32_16x16x32_bf16(wp[0], bf, acc0, 0, 0, 0);
            acc1 = __builtin_amdgcn_mfma_f32_16x16x32_bf16(wp[64], bf, acc1, 0, 0, 0);
        }
    }
#pragma unroll
    for (int r = 0; r < 4; ++r) {
        int oc = (lane >> 4) * 4 + r;
        offs[(((size_t)b * 18 + oc) * 64 + h) * 64 + px] = acc0[r] + b_off[oc];
    }
#pragma unroll
    for (int r = 0; r < 4; ++r) {
        int oc = 16 + (lane >> 4) * 4 + r;
        if (oc < 18)
            offs[(((size_t)b * 18 + oc) * 64 + h) * 64 + px] = acc1[r] + b_off[oc];
    }
}

// ---------- fused bilinear gather + MFMA GEMM, software-pipelined ----------
__global__ __launch_bounds__(256, 2) void k_deform3(const unsigned short* __restrict__ xT,
                                                    const unsigned short* __restrict__ wfrag,
                                                    const float* __restrict__ offs,
                                                    float* __restrict__ out) {
    int bh = blockIdx.x;
    int b = bh & 7, h = bh >> 3;
    int tid = threadIdx.x, lane = tid & 63, wm = tid >> 6;

    __shared__ float s_py[9][64], s_px[9][64];
    __shared__ __align__(16) unsigned short s_samp[2][64 * 64];

    for (int idx = tid; idx < 576; idx += 256) {
        int k2 = idx >> 6, p = idx & 63;
        float dy = offs[(((size_t)b * 18 + k2 * 2 + 0) * 64 + h) * 64 + p];
        float dx = offs[(((size_t)b * 18 + k2 * 2 + 1) * 64 + h) * 64 + p];
        s_py[k2][p] = (float)(h - 1 + k2 / 3) + dy;
        s_px[k2][p] = (float)(p - 1 + k2 % 3) + dx;
    }
    __syncthreads();

    f32x4 acc[4][4];
#pragma unroll
    for (int i = 0; i < 4; ++i)
#pragma unroll
        for (int j = 0; j < 4; ++j) acc[i][j] = (f32x4){0.f, 0.f, 0.f, 0.f};

    const unsigned short* xb = xT + (size_t)b * HW_ * C_;

    float w00, w01, w10, w11;
    int i00, i01, i10, i11;
    bf16x8 a0, a1, a2, a3, a4, a5, a6, a7;

#define GEOM(K2)                                                                  \
    {                                                                             \
        float py = s_py[K2][lane], pxx = s_px[K2][lane];                          \
        float y0f = floorf(py), x0f = floorf(pxx);                                \
        float wy = py - y0f, wx = pxx - x0f;                                      \
        int y0 = (int)y0f, x0 = (int)x0f;                                         \
        w00 = (1.f - wy) * (1.f - wx); w01 = (1.f - wy) * wx;                     \
        w10 = wy * (1.f - wx); w11 = wy * wx;                                     \
        bool vy0 = (unsigned)y0 < 64u, vy1 = (unsigned)(y0 + 1) < 64u;            \
        bool vx0 = (unsigned)x0 < 64u, vx1 = (unsigned)(x0 + 1) < 64u;            \
        if (!(vy0 && vx0)) w00 = 0.f;                                             \
        if (!(vy0 && vx1)) w01 = 0.f;                                             \
        if (!(vy1 && vx0)) w10 = 0.f;                                             \
        if (!(vy1 && vx1)) w11 = 0.f;                                             \
        int y0c = y0 < 0 ? 0 : (y0 > 63 ? 63 : y0);                               \
        int y1c = (y0 + 1) < 0 ? 0 : ((y0 + 1) > 63 ? 63 : (y0 + 1));             \
        int x0c = x0 < 0 ? 0 : (x0 > 63 ? 63 : x0);                               \
        int x1c = (x0 + 1) < 0 ? 0 : ((x0 + 1) > 63 ? 63 : (x0 + 1));             \
        i00 = (y0c * 64 + x0c) * C_; i01 = (y0c * 64 + x1c) * C_;                 \
        i10 = (y1c * 64 + x0c) * C_; i11 = (y1c * 64 + x1c) * C_;                 \
    }

#define ISSUE(S)                                                                  \
    {                                                                             \
        int ch0 = ((S) & 3) * 64 + wm * 8;                                        \
        a0 = *reinterpret_cast<const bf16x8*>(xb + i00 + ch0);                    \
        a1 = *reinterpret_cast<const bf16x8*>(xb + i01 + ch0);                    \
        a2 = *reinterpret_cast<const bf16x8*>(xb + i10 + ch0);                    \
        a3 = *reinterpret_cast<const bf16x8*>(xb + i11 + ch0);                    \
        a4 = *reinterpret_cast<const bf16x8*>(xb + i00 + ch0 + 32);               \
        a5 = *reinterpret_cast<const bf16x8*>(xb + i01 + ch0 + 32);               \
        a6 = *reinterpret_cast<const bf16x8*>(xb + i10 + ch0 + 32);               \
        a7 = *reinterpret_cast<const bf16x8*>(xb + i11 + ch0 + 32);               \
    }

#define PACK(BUF)                                                                 \
    {                                                                             \
        bf16x8 pk0, pk1;                                                          \
        _Pragma("unroll") for (int j = 0; j < 8; ++j)                             \
        {                                                                         \
            float s0 = w00 * bf2f(a0[j]) + w01 * bf2f(a1[j]) +                    \
                       w10 * bf2f(a2[j]) + w11 * bf2f(a3[j]);                     \
            float s1 = w00 * bf2f(a4[j]) + w01 * bf2f(a5[j]) +                    \
                       w10 * bf2f(a6[j]) + w11 * bf2f(a7[j]);                     \
            pk0[j] = (short)f2bf(s0);                                             \
            pk1[j] = (short)f2bf(s1);                                             \
        }                                                                         \
        int sl0 = (wm ^ (lane & 7)) & 7;                                          \
        int sl1 = ((wm + 4) ^ (lane & 7)) & 7;                                    \
        *reinterpret_cast<bf16x8*>(&s_samp[BUF][lane * 64 + sl0 * 8]) = pk0;      \
        *reinterpret_cast<bf16x8*>(&s_samp[BUF][lane * 64 + sl1 * 8]) = pk1;      \
    }

    // prologue: step 0
    GEOM(0);
    ISSUE(0);
    PACK(0);

#pragma unroll 2
    for (int s = 0; s < 36; ++s) {
        // A-fragment loads for step s (issued FIRST so MFMA waits only on these)
        bf16x8 afr[2][4];
        const bf16x8* wf = reinterpret_cast<const bf16x8*>(wfrag) +
                           (size_t)(s * 2 * 16 + wm * 4) * 64 + lane;
#pragma unroll
        for (int kk = 0; kk < 2; ++kk)
#pragma unroll
            for (int mf = 0; mf < 4; ++mf)
                afr[kk][mf] = wf[(size_t)(kk * 16 + mf) * 64];

        int nxt = s + 1;
        if (nxt < 36) {
            if ((nxt & 3) == 0) GEOM(nxt >> 2);
            ISSUE(nxt);  // 8 gather loads stay in flight across barrier + MFMA
        }
        __syncthreads();

        bf16x8 bfr[2][4];
        int bsel = s & 1;
#pragma unroll
        for (int kk = 0; kk < 2; ++kk)
#pragma unroll
            for (int nf = 0; nf < 4; ++nf) {
                int n = nf * 16 + (lane & 15);
                int oct = kk * 4 + (lane >> 4);
                int slot = (oct ^ (n & 7)) & 7;
                bfr[kk][nf] = *reinterpret_cast<const bf16x8*>(&s_samp[bsel][n * 64 + slot * 8]);
            }
#pragma unroll
        for (int kk = 0; kk < 2; ++kk)
#pragma unroll
            for (int mf = 0; mf < 4; ++mf)
#pragma unroll
                for (int nf = 0; nf < 4; ++nf)
                    acc[mf][nf] = __builtin_amdgcn_mfma_f32_16x16x32_bf16(
                        afr[kk][mf], bfr[kk][nf], acc[mf][nf], 0, 0, 0);

        if (nxt < 36) PACK(nxt & 1);
    }

    float* op = out + (size_t)b * O_ * HW_ + h * 64;
#pragma unroll
    for (int mf = 0; mf < 4; ++mf)
#pragma unroll
        for (int nf = 0; nf < 4; ++nf)
#pragma unroll
            for (int r = 0; r < 4; ++r) {
                int o = wm * 64 + mf * 16 + (lane >> 4) * 4 + r;
                int w = nf * 16 + (lane & 15);
                op[(size_t)o * HW_ + w] = acc[mf][nf][r];
            }
}

extern "C" void kernel_launch(void* const* d_in, const int* in_sizes, int n_in,
                              void* d_out, int out_size, void* d_ws, size_t ws_size,
                              hipStream_t stream) {
    const float* x = (const float*)d_in[0];
    const float* w_off = (const float*)d_in[1];
    const float* b_off = (const float*)d_in[2];
    const float* w_def = (const float*)d_in[3];
    float* out = (float*)d_out;
    char* ws = (char*)d_ws;

    float* offs = (float*)ws;                                             // 2,359,296 B
    unsigned short* xT = (unsigned short*)(ws + 2359296);                 // 16,777,216 B
    unsigned short* wfrag = (unsigned short*)(ws + 2359296 + 16777216);   // 1,179,648 B
    unsigned short* wofr = (unsigned short*)(ws + 2359296 + 16777216 + 1179648); // 147,456 B

    k_nhwc<<<512, 256, 0, stream>>>(x, xT);
    k_prep_wdef<<<288, 256, 0, stream>>>(w_def, wfrag);
    k_prep_woffrag<<<36, 256, 0, stream>>>(w_off, wofr);
    k_offconv3<<<512, 256, 0, stream>>>(xT, wofr, b_off, offs);
    k_deform3<<<512, 256, 0, stream>>>(xT, wfrag, offs, out);
}